// Round 1
// 80.943 us; speedup vs baseline: 1.0034x; 1.0034x over previous
//
#include <hip/hip_runtime.h>
#include <stdint.h>

#define HH 96
#define WW 96
#define NN (HH*WW)
#define NW 192   // bitmap words: 96 rows x 2 (128-bit padded rows, cols 96..127 dead)
#define NMT 24   // m-tiles for rank partials
#define MT 384   // m-tile size (NMT*MT == NN)
#define NKT 9    // k-tiles of 1024 (NKT*1024 == NN)

// ws layout (bytes):
//   [0,      884736)  rankp u32[24][9216]  exact stable-rank partials
//   [884736, 886272)  kw    u64[192]       kept bitmap words

__device__ __forceinline__ int coord1(int a) { return (10 * a + 1) / 3; }

// Aligned shifted word: result bit b (cell col 64h+b) = src-row bit (64h+b+dj).
__device__ __forceinline__ unsigned long long shifted(unsigned long long A,
                                                      unsigned long long B,
                                                      int h, int dj) {
    const unsigned long long W0 = h ? B : A;
    if (dj == 0) return W0;
    if (dj > 0) {
        const unsigned long long Wr = h ? 0ULL : B;
        return (W0 >> dj) | (Wr << (64 - dj));
    }
    const int d = -dj;
    const unsigned long long Wl = h ? A : 0ULL;
    return (W0 << d) | (Wl >> (64 - d));
}

// One dispatch, disjoint block roles, ZERO cross-block sync (R6/R8 lesson).
// Block 0: bit-parallel greedy NMS (longest block -> dispatched first).
// Blocks 1..216: exact stable-rank partials via u64 packed keys
//   key = (score_bits<<14) | (16383-idx):  key_m > key_k  <=>
//   (b_m > b_k) || (b_m==b_k && m<k)  -- single v_cmp_lt_u64 per element
//   (uniform[0,1) scores are non-negative: IEEE bits order-isomorphic).
// NMS tiebreak v<c has constant sign per edge (v-c = dj+96*di fixed), so the
// mask-build compare is a single unsigned compare per edge.
__global__ __launch_bounds__(1024, 1) void kA(const float* __restrict__ cls,
                                              unsigned int* __restrict__ rankp,
                                              unsigned long long* __restrict__ kw) {
    __shared__ __align__(16) float s[NN];         // 36 KB (rank blocks alias 3 KB)
    __shared__ unsigned long long Hh[12][NW];     // 18 KB
    __shared__ unsigned long long K[NW], D[NW];   // 3 KB
    const int tid = threadIdx.x;
    const int bid = blockIdx.x;

    if (bid != 0) {
        // ---- rank partials: (k-tile of 1024) x (m-tile of 384) ----
        const int rb = bid - 1;
        const int kt = rb % NKT, mt = rb / NKT;
        const int base = mt * MT;
        unsigned long long* sk = (unsigned long long*)s;
        if (tid < MT) {
            const int m = base + tid;
            sk[tid] = ((unsigned long long)__float_as_uint(cls[m]) << 14)
                    | (unsigned long long)(16383 - m);
        }
        __syncthreads();
        const int k = kt * 1024 + tid;
        const unsigned long long kk =
            ((unsigned long long)__float_as_uint(cls[k]) << 14)
          | (unsigned long long)(16383 - k);
        const ulonglong2* sk2 = (const ulonglong2*)sk;
        unsigned c0 = 0, c1 = 0;
        #pragma unroll 4
        for (int m2 = 0; m2 < MT / 2; ++m2) {
            const ulonglong2 v = sk2[m2];   // broadcast read, conflict-free
            c0 += (v.x > kk);
            c1 += (v.y > kk);
        }
        rankp[mt * NN + k] = c0 + c1;
        return;
    }

    // ---- NMS block (bid == 0) ----
    const int lane = tid & 63;
    const int wave = tid >> 6;
    const int offs_di[12] = {0,0, 0,0, -1,1, -2,2, -1,-1, 1,1};
    const int offs_dj[12] = {-1,1,-2,2,  0,0,  0,0, -1, 1,-1,1};
    for (int i = tid; i < NN/4; i += 1024)
        ((float4*)s)[i] = ((const float4*)cls)[i];
    __syncthreads();
    // Build H masks + K/D init via ballot. Word w: row w>>1, col base 64*(w&1);
    // lane l <-> col base+l. 16 waves x 12 iters = 192 words. Geometry folded
    // to (col%3,row%3) patterns (R11-validated, absmax=0).
    for (int it = 0; it < 12; ++it) {
        const int w = wave + (it << 4);
        const int row = w >> 1;
        const int col = ((w & 1) << 6) + lane;
        const bool incell = (col < WW);
        const int c = row * WW + col;
        const float sc = incell ? s[c] : 0.0f;
        const unsigned bc = __float_as_uint(sc);
        const int cm3 = col % 3, rm3 = row % 3;
        const unsigned long long dinit = __ballot(!incell || !(sc > 0.6f));
        if (lane == 0) { D[w] = dinit; K[w] = 0ULL; }
        #pragma unroll
        for (int e = 0; e < 12; ++e) {
            const int ii = row + offs_di[e], jj = col + offs_dj[e];
            bool geo;
            switch (e) {
                case 2:  geo = (cm3 == 1); break;              // (0,-2)
                case 3:  geo = (cm3 == 2); break;              // (0,+2)
                case 6:  geo = (rm3 == 1); break;              // (-2,0)
                case 7:  geo = (rm3 == 2); break;              // (+2,0)
                case 8:  geo = !(cm3 == 2 && rm3 == 2); break; // (-1,-1)
                case 9:  geo = !(cm3 == 1 && rm3 == 2); break; // (-1,+1)
                case 10: geo = !(cm3 == 2 && rm3 == 1); break; // (+1,-1)
                case 11: geo = !(cm3 == 1 && rm3 == 1); break; // (+1,+1)
                default: geo = true;                           // step-1 edges
            }
            // tiebreak v<c is a compile-time constant per edge:
            // true  for e in {0,2,4,6,8,9}  (di<0 || (di==0 && dj<0))
            const bool tb = (e==0)|(e==2)|(e==4)|(e==6)|(e==8)|(e==9);
            bool hp = false;
            if (incell && geo && ii >= 0 && ii < HH && jj >= 0 && jj < WW) {
                const unsigned bv = __float_as_uint(s[ii * WW + jj]);
                hp = tb ? (bv >= bc) : (bv > bc);
            }
            const unsigned long long m = __ballot(hp);
            if (lane == 0) Hh[e][w] = m;
        }
    }
    __syncthreads();          // last barrier: all 16 waves present
    if (wave >= 3) return;    // waves 3..15 done; 0..2 free-run (no barriers)

    // Free-running monotone fixpoint (R10-validated): thread w owns word w.
    // Write order K-then-D, read order D-then-K: LDS applies per-wave ops in
    // order and volatile preserves program order, so D=1 observed => that
    // neighbor's K is current (no false "determined-not-kept").
    volatile unsigned long long* vK = K;
    volatile unsigned long long* vD = D;
    const int w = tid;
    const int row = w >> 1, h = w & 1;
    unsigned long long Hr[12];
    #pragma unroll
    for (int e = 0; e < 12; ++e) Hr[e] = Hh[e][w];
    unsigned long long myK = K[w], myD = D[w];    // own words: only this thread writes
    for (int iter = 0; iter < 4096; ++iter) {
        if (!~myD) break;                          // fully determined: final
        unsigned long long DA[5], DB[5], KA[5], KB[5];
        #pragma unroll
        for (int q = 0; q < 5; ++q) {              // D reads FIRST
            const int rr = row + q - 2;
            const bool ok = (rr >= 0) && (rr < HH);
            DA[q] = ok ? vD[rr*2]   : 0ULL;
            DB[q] = ok ? vD[rr*2+1] : 0ULL;        // out-of-grid: H=0 there anyway
        }
        #pragma unroll
        for (int q = 0; q < 5; ++q) {              // K reads AFTER D
            const int rr = row + q - 2;
            const bool ok = (rr >= 0) && (rr < HH);
            KA[q] = ok ? vK[rr*2]   : 0ULL;
            KB[q] = ok ? vK[rr*2+1] : 0ULL;
        }
        unsigned long long supp = 0ULL, alldet = ~0ULL;
        #pragma unroll
        for (int e = 0; e < 12; ++e) {
            const int q = offs_di[e] + 2;
            const int dj = offs_dj[e];
            supp   |=  Hr[e] & shifted(KA[q], KB[q], h, dj);
            alldet &= ~Hr[e] | shifted(DA[q], DB[q], h, dj);
        }
        const unsigned long long U = ~myD;
        myK = myK | (U & alldet & ~supp);
        myD = myD | (U & (supp | alldet));
        vK[w] = myK;                               // K write BEFORE D write
        vD[w] = myD;
    }
    kw[w] = myK;   // own word final; no cross-wave read needed
}

// Epilogue: r = rank[k] is a permutation of [0,9216) — every output row
// written exactly once (non-kept rows -> zeros, no d_out memset needed).
__global__ void kout(const float* __restrict__ score, const float* __restrict__ reg,
                     const unsigned int* __restrict__ rankp,
                     const unsigned long long* __restrict__ kw,
                     float* __restrict__ out) {
    const int k = blockIdx.x * 256 + threadIdx.x;
    unsigned r = 0;
    #pragma unroll
    for (int y = 0; y < NMT; ++y) r += rankp[y * NN + k];
    const int j = k % WW, i = k / WW;
    const bool kp = ((kw[i * 2 + (j >> 6)] >> (j & 63)) & 1ULL) != 0ULL;
    const float x1 = (float)coord1(j);
    const float y1 = (float)coord1(i);
    const float4 d = ((const float4*)reg)[k];
    float* o = out + (size_t)r * 5;
    o[0] = kp ? (x1 + d.x * 21.0f) : 0.0f;
    o[1] = kp ? (y1 + d.y * 21.0f) : 0.0f;
    o[2] = kp ? (x1 + 20.0f + d.z * 21.0f) : 0.0f;
    o[3] = kp ? (y1 + 20.0f + d.w * 21.0f) : 0.0f;
    o[4] = kp ? score[k] : 0.0f;
}

extern "C" void kernel_launch(void* const* d_in, const int* in_sizes, int n_in,
                              void* d_out, int out_size, void* d_ws, size_t ws_size,
                              hipStream_t stream) {
    const float* cls = (const float*)d_in[0];
    const float* reg = (const float*)d_in[1];
    float* out = (float*)d_out;
    char* ws = (char*)d_ws;
    unsigned int* rankp = (unsigned int*)(ws);
    unsigned long long* kw = (unsigned long long*)(ws + 884736);

    kA<<<217, 1024, 0, stream>>>(cls, rankp, kw);
    kout<<<36, 256, 0, stream>>>(cls, reg, rankp, kw, out);
}

// Round 2
// 79.469 us; speedup vs baseline: 1.0220x; 1.0185x over previous
//
#include <hip/hip_runtime.h>
#include <stdint.h>

#define HH 96
#define WW 96
#define NN (HH*WW)
#define NW 192   // bitmap words: 96 rows x 2 (128-bit padded rows, cols 96..127 dead)
#define NMT 24   // m-tiles for rank partials
#define MT 384   // m-tile size (NMT*MT == NN)
#define NKT 9    // k-tiles of 1024 (NKT*1024 == NN)

// ws layout (bytes):
//   [0,      884736)  rankp u32[24][9216]  exact stable-rank partials
//   [884736, 886272)  kw    u64[192]       kept bitmap words

__device__ __forceinline__ int coord1(int a) { return (10 * a + 1) / 3; }

// Compile-time-specialized shifted word for half H, col shift DJ.
// 128-bit row = (A low cols 0..63, B high cols 64..127); S = own-half word,
// O = other-half word. Result bit b (cell col 64H+b) = row bit (64H+b+DJ).
template<int H, int DJ>
__device__ __forceinline__ unsigned long long shf(unsigned long long S,
                                                  unsigned long long O) {
    if constexpr (DJ == 0) {
        return S;
    } else if constexpr (H == 0) {
        if constexpr (DJ > 0) return (S >> DJ) | (O << (64 - DJ));  // B feeds high bits
        else                  return (S << (-DJ));                  // left of A is 0
    } else {
        if constexpr (DJ > 0) return (S >> DJ);                     // right of B is 0
        else                  return (S << (-DJ)) | (O >> (64 + DJ)); // A feeds low bits
    }
}

// Free-running monotone fixpoint (R10 protocol preserved): one thread per
// word, h compile-time per wave. Write K-then-D, read D-then-K, volatile:
// D=1 observed => that word's K is current. Own word lives in registers
// (strictly fresher than LDS; monotone-safe).
template<int H>
__device__ __forceinline__ unsigned long long runfix(
    const int row, const unsigned long long (&Hr)[12],
    volatile unsigned long long* vKs, volatile unsigned long long* vKo,
    volatile unsigned long long* vDs, volatile unsigned long long* vDo,
    unsigned long long myK, unsigned long long myD) {
    const bool okm1 = row >= 1, okp1 = row <= HH - 2;
    const bool okm2 = row >= 2, okp2 = row <= HH - 3;
    for (int iter = 0; iter < 4096; ++iter) {
        if (!~myD) break;                          // fully determined: final
        // ---- D reads FIRST (out-of-grid rows: H=0 there anyway) ----
        const unsigned long long D0o  = vDo[row];
        const unsigned long long Dm1s = okm1 ? vDs[row-1] : 0ULL;
        const unsigned long long Dm1o = okm1 ? vDo[row-1] : 0ULL;
        const unsigned long long Dp1s = okp1 ? vDs[row+1] : 0ULL;
        const unsigned long long Dp1o = okp1 ? vDo[row+1] : 0ULL;
        const unsigned long long Dm2  = okm2 ? vDs[row-2] : 0ULL;
        const unsigned long long Dp2  = okp2 ? vDs[row+2] : 0ULL;
        // ---- K reads AFTER D ----
        const unsigned long long K0o  = vKo[row];
        const unsigned long long Km1s = okm1 ? vKs[row-1] : 0ULL;
        const unsigned long long Km1o = okm1 ? vKo[row-1] : 0ULL;
        const unsigned long long Kp1s = okp1 ? vKs[row+1] : 0ULL;
        const unsigned long long Kp1o = okp1 ? vKo[row+1] : 0ULL;
        const unsigned long long Km2  = okm2 ? vKs[row-2] : 0ULL;
        const unsigned long long Kp2  = okp2 ? vKs[row+2] : 0ULL;

        unsigned long long supp = 0ULL;
        supp |= Hr[0]  & shf<H,-1>(myK,  K0o);     // (0,-1)
        supp |= Hr[1]  & shf<H,+1>(myK,  K0o);     // (0,+1)
        supp |= Hr[2]  & shf<H,-2>(myK,  K0o);     // (0,-2)
        supp |= Hr[3]  & shf<H,+2>(myK,  K0o);     // (0,+2)
        supp |= Hr[4]  & Km1s;                     // (-1,0)
        supp |= Hr[5]  & Kp1s;                     // (+1,0)
        supp |= Hr[6]  & Km2;                      // (-2,0)
        supp |= Hr[7]  & Kp2;                      // (+2,0)
        supp |= Hr[8]  & shf<H,-1>(Km1s, Km1o);    // (-1,-1)
        supp |= Hr[9]  & shf<H,+1>(Km1s, Km1o);    // (-1,+1)
        supp |= Hr[10] & shf<H,-1>(Kp1s, Kp1o);    // (+1,-1)
        supp |= Hr[11] & shf<H,+1>(Kp1s, Kp1o);    // (+1,+1)

        unsigned long long alldet = ~0ULL;
        alldet &= ~Hr[0]  | shf<H,-1>(myD,  D0o);
        alldet &= ~Hr[1]  | shf<H,+1>(myD,  D0o);
        alldet &= ~Hr[2]  | shf<H,-2>(myD,  D0o);
        alldet &= ~Hr[3]  | shf<H,+2>(myD,  D0o);
        alldet &= ~Hr[4]  | Dm1s;
        alldet &= ~Hr[5]  | Dp1s;
        alldet &= ~Hr[6]  | Dm2;
        alldet &= ~Hr[7]  | Dp2;
        alldet &= ~Hr[8]  | shf<H,-1>(Dm1s, Dm1o);
        alldet &= ~Hr[9]  | shf<H,+1>(Dm1s, Dm1o);
        alldet &= ~Hr[10] | shf<H,-1>(Dp1s, Dp1o);
        alldet &= ~Hr[11] | shf<H,+1>(Dp1s, Dp1o);

        const unsigned long long U = ~myD;
        myK |= U & alldet & ~supp;
        myD |= U & (supp | alldet);
        vKs[row] = myK;                            // K write BEFORE D write
        vDs[row] = myD;
    }
    return myK;
}

// One dispatch, disjoint block roles, ZERO cross-block sync (R6/R8 lesson).
// Block 0: bit-parallel greedy NMS (longest block -> dispatched first).
// Blocks 1..216: exact stable-rank partials via u64 packed keys
//   key = (score_bits<<14) | (16383-idx):  key_m > key_k  <=>
//   (b_m > b_k) || (b_m==b_k && m<k)  -- single 64-bit compare per element.
__global__ __launch_bounds__(1024, 1) void kA(const float* __restrict__ cls,
                                              unsigned int* __restrict__ rankp,
                                              unsigned long long* __restrict__ kw) {
    __shared__ __align__(16) float s[NN];         // 36 KB (rank blocks alias 3 KB)
    __shared__ unsigned long long Hh[12][NW];     // 18 KB
    __shared__ unsigned long long K2[2][HH], D2[2][HH];   // [h][row], 3 KB
    const int tid = threadIdx.x;
    const int bid = blockIdx.x;

    if (bid != 0) {
        // ---- rank partials: (k-tile of 1024) x (m-tile of 384) ----
        const int rb = bid - 1;
        const int kt = rb % NKT, mt = rb / NKT;
        const int base = mt * MT;
        unsigned long long* sk = (unsigned long long*)s;
        if (tid < MT) {
            const int m = base + tid;
            sk[tid] = ((unsigned long long)__float_as_uint(cls[m]) << 14)
                    | (unsigned long long)(16383 - m);
        }
        __syncthreads();
        const int k = kt * 1024 + tid;
        const unsigned long long kk =
            ((unsigned long long)__float_as_uint(cls[k]) << 14)
          | (unsigned long long)(16383 - k);
        const ulonglong2* sk2 = (const ulonglong2*)sk;
        unsigned c0 = 0, c1 = 0;
        #pragma unroll 4
        for (int m2 = 0; m2 < MT / 2; ++m2) {
            const ulonglong2 v = sk2[m2];   // broadcast read, conflict-free
            c0 += (v.x > kk);
            c1 += (v.y > kk);
        }
        rankp[mt * NN + k] = c0 + c1;
        return;
    }

    // ---- NMS block (bid == 0) ----
    const int lane = tid & 63;
    const int wave = tid >> 6;
    const int offs_di[12] = {0,0, 0,0, -1,1, -2,2, -1,-1, 1,1};
    const int offs_dj[12] = {-1,1,-2,2,  0,0,  0,0, -1, 1,-1,1};
    for (int i = tid; i < NN/4; i += 1024)
        ((float4*)s)[i] = ((const float4*)cls)[i];
    __syncthreads();
    // Build H masks + K/D init via ballot. Word w: row w>>1, col base 64*(w&1);
    // lane l <-> col base+l. 16 waves x 12 iters = 192 words. Geometry folded
    // to (col%3,row%3) patterns (R11-validated, absmax=0).
    for (int it = 0; it < 12; ++it) {
        const int w = wave + (it << 4);
        const int row = w >> 1;
        const int col = ((w & 1) << 6) + lane;
        const bool incell = (col < WW);
        const int c = row * WW + col;
        const float sc = incell ? s[c] : 0.0f;
        const unsigned bc = __float_as_uint(sc);
        const int cm3 = col % 3, rm3 = row % 3;
        const unsigned long long dinit = __ballot(!incell || !(sc > 0.6f));
        if (lane == 0) { D2[w & 1][w >> 1] = dinit; K2[w & 1][w >> 1] = 0ULL; }
        #pragma unroll
        for (int e = 0; e < 12; ++e) {
            const int ii = row + offs_di[e], jj = col + offs_dj[e];
            bool geo;
            switch (e) {
                case 2:  geo = (cm3 == 1); break;              // (0,-2)
                case 3:  geo = (cm3 == 2); break;              // (0,+2)
                case 6:  geo = (rm3 == 1); break;              // (-2,0)
                case 7:  geo = (rm3 == 2); break;              // (+2,0)
                case 8:  geo = !(cm3 == 2 && rm3 == 2); break; // (-1,-1)
                case 9:  geo = !(cm3 == 1 && rm3 == 2); break; // (-1,+1)
                case 10: geo = !(cm3 == 2 && rm3 == 1); break; // (+1,-1)
                case 11: geo = !(cm3 == 1 && rm3 == 1); break; // (+1,+1)
                default: geo = true;                           // step-1 edges
            }
            // tiebreak v<c is a compile-time constant per edge:
            // true  for e in {0,2,4,6,8,9}  (di<0 || (di==0 && dj<0))
            const bool tb = (e==0)|(e==2)|(e==4)|(e==6)|(e==8)|(e==9);
            bool hp = false;
            if (incell && geo && ii >= 0 && ii < HH && jj >= 0 && jj < WW) {
                const unsigned bv = __float_as_uint(s[ii * WW + jj]);
                hp = tb ? (bv >= bc) : (bv > bc);
            }
            const unsigned long long m = __ballot(hp);
            if (lane == 0) Hh[e][w] = m;
        }
    }
    __syncthreads();          // last barrier: all 16 waves present
    // Fixpoint threads: 4 waves x 48 lanes; h = wave>>1 is WAVE-UNIFORM so
    // the loop is compile-time specialized by half (no runtime h selects).
    if (wave >= 4 || lane >= 48) return;
    const int h2 = wave >> 1;
    const int row = ((wave & 1) * 48) + lane;
    unsigned long long Hr[12];
    #pragma unroll
    for (int e = 0; e < 12; ++e) Hr[e] = Hh[e][row * 2 + h2];
    const unsigned long long myK = K2[h2][row], myD = D2[h2][row];
    unsigned long long fin;
    if (h2 == 0)
        fin = runfix<0>(row, Hr,
                        (volatile unsigned long long*)&K2[0][0],
                        (volatile unsigned long long*)&K2[1][0],
                        (volatile unsigned long long*)&D2[0][0],
                        (volatile unsigned long long*)&D2[1][0], myK, myD);
    else
        fin = runfix<1>(row, Hr,
                        (volatile unsigned long long*)&K2[1][0],
                        (volatile unsigned long long*)&K2[0][0],
                        (volatile unsigned long long*)&D2[1][0],
                        (volatile unsigned long long*)&D2[0][0], myK, myD);
    kw[row * 2 + h2] = fin;   // own word final; no cross-wave read needed
}

// Epilogue: r = rank[k] is a permutation of [0,9216) — every output row
// written exactly once (non-kept rows -> zeros, no d_out memset needed).
__global__ void kout(const float* __restrict__ score, const float* __restrict__ reg,
                     const unsigned int* __restrict__ rankp,
                     const unsigned long long* __restrict__ kw,
                     float* __restrict__ out) {
    const int k = blockIdx.x * 256 + threadIdx.x;
    unsigned r = 0;
    #pragma unroll
    for (int y = 0; y < NMT; ++y) r += rankp[y * NN + k];
    const int j = k % WW, i = k / WW;
    const bool kp = ((kw[i * 2 + (j >> 6)] >> (j & 63)) & 1ULL) != 0ULL;
    const float x1 = (float)coord1(j);
    const float y1 = (float)coord1(i);
    const float4 d = ((const float4*)reg)[k];
    float* o = out + (size_t)r * 5;
    o[0] = kp ? (x1 + d.x * 21.0f) : 0.0f;
    o[1] = kp ? (y1 + d.y * 21.0f) : 0.0f;
    o[2] = kp ? (x1 + 20.0f + d.z * 21.0f) : 0.0f;
    o[3] = kp ? (y1 + 20.0f + d.w * 21.0f) : 0.0f;
    o[4] = kp ? score[k] : 0.0f;
}

extern "C" void kernel_launch(void* const* d_in, const int* in_sizes, int n_in,
                              void* d_out, int out_size, void* d_ws, size_t ws_size,
                              hipStream_t stream) {
    const float* cls = (const float*)d_in[0];
    const float* reg = (const float*)d_in[1];
    float* out = (float*)d_out;
    char* ws = (char*)d_ws;
    unsigned int* rankp = (unsigned int*)(ws);
    unsigned long long* kw = (unsigned long long*)(ws + 884736);

    kA<<<217, 1024, 0, stream>>>(cls, rankp, kw);
    kout<<<36, 256, 0, stream>>>(cls, reg, rankp, kw, out);
}

// Round 3
// 73.238 us; speedup vs baseline: 1.1090x; 1.0851x over previous
//
#include <hip/hip_runtime.h>
#include <stdint.h>

#define HH 96
#define WW 96
#define NN (HH*WW)
#define NW 192   // bitmap words: 96 rows x 2 (128-bit padded rows, cols 96..127 dead)
#define NMT 72   // m-tiles for rank partials
#define MT 128   // m-tile size (NMT*MT == NN)
#define NKT 3    // k-tiles of 3072 (3 keys/thread)
#define KW_OFF 2654208   // 72*9216*4

// ws layout (bytes):
//   [0, 2654208)        rankp u32[72][9216]  exact stable-rank partials
//   [2654208, 2655744)  kw    u64[192]       kept bitmap words

__device__ __forceinline__ int coord1(int a) { return (10 * a + 1) / 3; }

// Compile-time-specialized shifted word for half H, col shift DJ.
// 128-bit row = (A low cols 0..63, B high cols 64..127); S = own-half word,
// O = other-half word. Result bit b (cell col 64H+b) = row bit (64H+b+DJ).
template<int H, int DJ>
__device__ __forceinline__ unsigned long long shf(unsigned long long S,
                                                  unsigned long long O) {
    if constexpr (DJ == 0) {
        return S;
    } else if constexpr (H == 0) {
        if constexpr (DJ > 0) return (S >> DJ) | (O << (64 - DJ));  // B feeds high bits
        else                  return (S << (-DJ));                  // left of A is 0
    } else {
        if constexpr (DJ > 0) return (S >> DJ);                     // right of B is 0
        else                  return (S << (-DJ)) | (O >> (64 + DJ)); // A feeds low bits
    }
}

// Column-geometry masks: bit b set iff cm3(col 64H+b) == 1 (C1) / == 2 (C2).
template<int H> struct CM;
template<> struct CM<0> {
    static constexpr unsigned long long C1 = 0x2492492492492492ULL;  // b%3==1
    static constexpr unsigned long long C2 = 0x4924924924924924ULL;  // b%3==2
};
template<> struct CM<1> {
    static constexpr unsigned long long C1 = 0x9249249249249249ULL;  // (b+64)%3==1
    static constexpr unsigned long long C2 = 0x2492492492492492ULL;  // (b+64)%3==2
};

// Free-running monotone fixpoint (R10 protocol preserved): one thread per
// word, h compile-time per wave. Write K-then-D, read D-then-K, volatile:
// D=1 observed => that word's K is current. Own word lives in registers.
// Derived H edges: H[+e] = ~shifted(H[-e]) & geo-mask (exact under the
// tiebreak sign convention); spurious complement bits only hit dead cells /
// padding cols (D=1,K=0 from init -> harmless), col-0 dj=-1 masked.
// Inner 3x relaxation: horizontal edges re-applied with fresh own word
// (monotone-safe with the stale-but-ordered neighbor snapshot).
template<int H>
__device__ __forceinline__ unsigned long long runfix(
    const int row, const unsigned long long* Hc,
    volatile unsigned long long* vKs, volatile unsigned long long* vKo,
    volatile unsigned long long* vDs, volatile unsigned long long* vDo,
    unsigned long long myK, unsigned long long myD) {
    const int w  = row * 2 + H;
    const int wo = row * 2 + (H ^ 1);
    const bool okm1 = row >= 1, okp1 = row <= HH - 2;
    const bool okm2 = row >= 2, okp2 = row <= HH - 3;
    const int rm3 = row % 3;
    unsigned long long Hr[12];
    {
        const unsigned long long h0s = Hc[0*NW+w], h0o = Hc[0*NW+wo];
        const unsigned long long h2s = Hc[1*NW+w], h2o = Hc[1*NW+wo];
        Hr[0] = h0s;                                  // (0,-1) computed
        Hr[1] = ~shf<H,1>(h0s, h0o);                  // (0,+1) derived
        Hr[2] = h2s;                                  // (0,-2) computed
        Hr[3] = (~shf<H,2>(h2s, h2o)) & CM<H>::C2;    // (0,+2) derived, geo cm3==2
        Hr[4] = Hc[2*NW+w];                           // (-1,0) computed
        Hr[6] = Hc[3*NW+w];                           // (-2,0) computed
        Hr[8] = Hc[4*NW+w];                           // (-1,-1) computed
        Hr[9] = Hc[5*NW+w];                           // (-1,+1) computed
        Hr[5] = okp1 ? ~Hc[2*NW+w+2] : 0ULL;          // (+1,0) derived
        Hr[7] = (okp2 && rm3 == 2) ? ~Hc[3*NW+w+4] : 0ULL;  // (+2,0) derived
        if (okp1) {
            const unsigned long long a8 = Hc[4*NW+w+2], b8 = Hc[4*NW+wo+2];
            unsigned long long t11 = ~shf<H,1>(a8, b8);    // (+1,+1) from (-1,-1)@r+1
            const unsigned long long a9 = Hc[5*NW+w+2], b9 = Hc[5*NW+wo+2];
            unsigned long long t10 = ~shf<H,-1>(a9, b9);   // (+1,-1) from (-1,+1)@r+1
            if (rm3 == 1) { t11 &= ~CM<H>::C1; t10 &= ~CM<H>::C2; }
            if constexpr (H == 0) t10 &= ~1ULL;            // col 0 has no col -1
            Hr[11] = t11; Hr[10] = t10;
        } else { Hr[11] = 0ULL; Hr[10] = 0ULL; }
    }
    for (int iter = 0; iter < 4096; ++iter) {
        if (!~myD) break;                          // fully determined: final
        // ---- D reads FIRST (out-of-grid rows: H=0 there anyway) ----
        const unsigned long long D0o  = vDo[row];
        const unsigned long long Dm1s = okm1 ? vDs[row-1] : 0ULL;
        const unsigned long long Dm1o = okm1 ? vDo[row-1] : 0ULL;
        const unsigned long long Dp1s = okp1 ? vDs[row+1] : 0ULL;
        const unsigned long long Dp1o = okp1 ? vDo[row+1] : 0ULL;
        const unsigned long long Dm2  = okm2 ? vDs[row-2] : 0ULL;
        const unsigned long long Dp2  = okp2 ? vDs[row+2] : 0ULL;
        // ---- K reads AFTER D ----
        const unsigned long long K0o  = vKo[row];
        const unsigned long long Km1s = okm1 ? vKs[row-1] : 0ULL;
        const unsigned long long Km1o = okm1 ? vKo[row-1] : 0ULL;
        const unsigned long long Kp1s = okp1 ? vKs[row+1] : 0ULL;
        const unsigned long long Kp1o = okp1 ? vKo[row+1] : 0ULL;
        const unsigned long long Km2  = okm2 ? vKs[row-2] : 0ULL;
        const unsigned long long Kp2  = okp2 ? vKs[row+2] : 0ULL;

        const unsigned long long suppV =
              (Hr[4]  & Km1s) | (Hr[5] & Kp1s) | (Hr[6] & Km2) | (Hr[7] & Kp2)
            | (Hr[8]  & shf<H,-1>(Km1s, Km1o)) | (Hr[9]  & shf<H,1>(Km1s, Km1o))
            | (Hr[10] & shf<H,-1>(Kp1s, Kp1o)) | (Hr[11] & shf<H,1>(Kp1s, Kp1o));
        unsigned long long alldetV = ~0ULL;
        alldetV &= ~Hr[4]  | Dm1s;
        alldetV &= ~Hr[5]  | Dp1s;
        alldetV &= ~Hr[6]  | Dm2;
        alldetV &= ~Hr[7]  | Dp2;
        alldetV &= ~Hr[8]  | shf<H,-1>(Dm1s, Dm1o);
        alldetV &= ~Hr[9]  | shf<H,1>(Dm1s, Dm1o);
        alldetV &= ~Hr[10] | shf<H,-1>(Dp1s, Dp1o);
        alldetV &= ~Hr[11] | shf<H,1>(Dp1s, Dp1o);

        #pragma unroll
        for (int in = 0; in < 3; ++in) {           // horizontal in-register relax
            const unsigned long long supp = suppV
                | (Hr[0] & shf<H,-1>(myK, K0o)) | (Hr[1] & shf<H,1>(myK, K0o))
                | (Hr[2] & shf<H,-2>(myK, K0o)) | (Hr[3] & shf<H,2>(myK, K0o));
            const unsigned long long alldet = alldetV
                & (~Hr[0] | shf<H,-1>(myD, D0o)) & (~Hr[1] | shf<H,1>(myD, D0o))
                & (~Hr[2] | shf<H,-2>(myD, D0o)) & (~Hr[3] | shf<H,2>(myD, D0o));
            const unsigned long long U = ~myD;
            myK |= U & alldet & ~supp;
            myD |= U & (supp | alldet);
        }
        vKs[row] = myK;                            // K write BEFORE D write
        vDs[row] = myD;
    }
    return myK;
}

// One dispatch, disjoint block roles, ZERO cross-block sync (R6/R8 lesson).
// Block 0: bit-parallel greedy NMS. Blocks 1..216: exact stable-rank
// partials via u64 packed keys, 3 k-keys per thread amortize each LDS
// broadcast read over 6 compares.
//   key = (score_bits<<14) | (16383-idx):  key_m > key_k  <=>
//   (b_m > b_k) || (b_m==b_k && m<k)  -- single 64-bit compare per element.
__global__ __launch_bounds__(1024, 1) void kA(const float* __restrict__ cls,
                                              unsigned int* __restrict__ rankp,
                                              unsigned long long* __restrict__ kw) {
    __shared__ __align__(16) float s[NN];         // 36 KB (rank blocks alias 1 KB)
    __shared__ unsigned long long Hc[6][NW];      // 9 KB (computed-edge masks)
    __shared__ unsigned long long K2[2][HH], D2[2][HH];   // [h][row], 3 KB
    const int tid = threadIdx.x;
    const int bid = blockIdx.x;

    if (bid != 0) {
        // ---- rank partials: (k-tile of 3072, 3 keys/thread) x (m-tile of 128) ----
        const int rb = bid - 1;
        const int kt = rb % NKT, mt = rb / NKT;
        const int base = mt * MT;
        unsigned long long* sk = (unsigned long long*)s;
        if (tid < MT) {
            const int m = base + tid;
            sk[tid] = ((unsigned long long)__float_as_uint(cls[m]) << 14)
                    | (unsigned long long)(16383 - m);
        }
        __syncthreads();
        const int k0 = kt * 3072 + tid;
        const unsigned long long kk0 =
            ((unsigned long long)__float_as_uint(cls[k0]) << 14)
          | (unsigned long long)(16383 - k0);
        const unsigned long long kk1 =
            ((unsigned long long)__float_as_uint(cls[k0 + 1024]) << 14)
          | (unsigned long long)(16383 - (k0 + 1024));
        const unsigned long long kk2 =
            ((unsigned long long)__float_as_uint(cls[k0 + 2048]) << 14)
          | (unsigned long long)(16383 - (k0 + 2048));
        const ulonglong2* sk2 = (const ulonglong2*)sk;
        unsigned a0 = 0, a1 = 0, a2 = 0;
        #pragma unroll 8
        for (int m2 = 0; m2 < MT / 2; ++m2) {
            const ulonglong2 v = sk2[m2];   // broadcast read, conflict-free
            a0 += (v.x > kk0) + (v.y > kk0);
            a1 += (v.x > kk1) + (v.y > kk1);
            a2 += (v.x > kk2) + (v.y > kk2);
        }
        unsigned int* rp = rankp + mt * NN + k0;
        rp[0] = a0; rp[1024] = a1; rp[2048] = a2;
        return;
    }

    // ---- NMS block (bid == 0) ----
    const int lane = tid & 63;
    const int wave = tid >> 6;
    for (int i = tid; i < NN/4; i += 1024)
        ((float4*)s)[i] = ((const float4*)cls)[i];
    __syncthreads();
    // Build 6 computed H masks (all tb=true: >=) + K/D init via ballot.
    // Word w: row w>>1, col base 64*(w&1); lane l <-> col base+l.
    // 16 waves x 12 iters = 192 words. Opposite edges derived in runfix.
    for (int it = 0; it < 12; ++it) {
        const int w = wave + (it << 4);
        const int row = w >> 1;
        const int col = ((w & 1) << 6) + lane;
        const bool incell = (col < WW);
        const int c = row * WW + col;
        const float sc = incell ? s[c] : 0.0f;
        const unsigned bc = __float_as_uint(sc);
        const int cm3 = col % 3, rm3 = row % 3;
        const unsigned long long dinit = __ballot(!incell || !(sc > 0.6f));
        if (lane == 0) { D2[w & 1][row] = dinit; K2[w & 1][row] = 0ULL; }
        const bool okl1 = col >= 1, okl2 = col >= 2, okr1 = col + 1 < WW;
        const bool oku1 = row >= 1, oku2 = row >= 2;
        bool hp; unsigned long long m;
        // c0 = (0,-1), geo true
        hp = false; if (incell && okl1) hp = __float_as_uint(s[c-1]) >= bc;
        m = __ballot(hp); if (lane == 0) Hc[0][w] = m;
        // c1 = (0,-2), geo cm3==1
        hp = false; if (incell && okl2 && cm3 == 1) hp = __float_as_uint(s[c-2]) >= bc;
        m = __ballot(hp); if (lane == 0) Hc[1][w] = m;
        // c2 = (-1,0), geo true
        hp = false; if (incell && oku1) hp = __float_as_uint(s[c-WW]) >= bc;
        m = __ballot(hp); if (lane == 0) Hc[2][w] = m;
        // c3 = (-2,0), geo rm3==1
        hp = false; if (incell && oku2 && rm3 == 1) hp = __float_as_uint(s[c-2*WW]) >= bc;
        m = __ballot(hp); if (lane == 0) Hc[3][w] = m;
        // c4 = (-1,-1), geo !(cm3==2&&rm3==2)
        hp = false; if (incell && oku1 && okl1 && !(cm3 == 2 && rm3 == 2))
            hp = __float_as_uint(s[c-WW-1]) >= bc;
        m = __ballot(hp); if (lane == 0) Hc[4][w] = m;
        // c5 = (-1,+1), geo !(cm3==1&&rm3==2)
        hp = false; if (incell && oku1 && okr1 && !(cm3 == 1 && rm3 == 2))
            hp = __float_as_uint(s[c-WW+1]) >= bc;
        m = __ballot(hp); if (lane == 0) Hc[5][w] = m;
    }
    __syncthreads();          // last barrier: all 16 waves present
    // Fixpoint threads: 4 waves x 48 lanes; h = wave>>1 is WAVE-UNIFORM so
    // the loop is compile-time specialized by half (no runtime h selects).
    if (wave >= 4 || lane >= 48) return;
    const int h2 = wave >> 1;
    const int row = ((wave & 1) * 48) + lane;
    const unsigned long long myK = K2[h2][row], myD = D2[h2][row];
    unsigned long long fin;
    if (h2 == 0)
        fin = runfix<0>(row, &Hc[0][0],
                        (volatile unsigned long long*)&K2[0][0],
                        (volatile unsigned long long*)&K2[1][0],
                        (volatile unsigned long long*)&D2[0][0],
                        (volatile unsigned long long*)&D2[1][0], myK, myD);
    else
        fin = runfix<1>(row, &Hc[0][0],
                        (volatile unsigned long long*)&K2[1][0],
                        (volatile unsigned long long*)&K2[0][0],
                        (volatile unsigned long long*)&D2[1][0],
                        (volatile unsigned long long*)&D2[0][0], myK, myD);
    kw[row * 2 + h2] = fin;   // own word final; no cross-wave read needed
}

// Epilogue: r = rank[k] is a permutation of [0,9216) — every output row
// written exactly once (non-kept rows -> zeros, no d_out memset needed).
__global__ void kout(const float* __restrict__ score, const float* __restrict__ reg,
                     const unsigned int* __restrict__ rankp,
                     const unsigned long long* __restrict__ kw,
                     float* __restrict__ out) {
    const int k = blockIdx.x * 256 + threadIdx.x;
    unsigned r = 0;
    #pragma unroll
    for (int y = 0; y < NMT; ++y) r += rankp[y * NN + k];
    const int j = k % WW, i = k / WW;
    const bool kp = ((kw[i * 2 + (j >> 6)] >> (j & 63)) & 1ULL) != 0ULL;
    const float x1 = (float)coord1(j);
    const float y1 = (float)coord1(i);
    const float4 d = ((const float4*)reg)[k];
    float* o = out + (size_t)r * 5;
    o[0] = kp ? (x1 + d.x * 21.0f) : 0.0f;
    o[1] = kp ? (y1 + d.y * 21.0f) : 0.0f;
    o[2] = kp ? (x1 + 20.0f + d.z * 21.0f) : 0.0f;
    o[3] = kp ? (y1 + 20.0f + d.w * 21.0f) : 0.0f;
    o[4] = kp ? score[k] : 0.0f;
}

extern "C" void kernel_launch(void* const* d_in, const int* in_sizes, int n_in,
                              void* d_out, int out_size, void* d_ws, size_t ws_size,
                              hipStream_t stream) {
    const float* cls = (const float*)d_in[0];
    const float* reg = (const float*)d_in[1];
    float* out = (float*)d_out;
    char* ws = (char*)d_ws;
    unsigned int* rankp = (unsigned int*)(ws);
    unsigned long long* kw = (unsigned long long*)(ws + KW_OFF);

    kA<<<1 + NKT * NMT, 1024, 0, stream>>>(cls, rankp, kw);
    kout<<<36, 256, 0, stream>>>(cls, reg, rankp, kw, out);
}